// Round 1
// 347.111 us; speedup vs baseline: 1.0504x; 1.0504x over previous
//
#include <hip/hip_runtime.h>
#include <hip/hip_fp16.h>

#define BSZ 1024   // B
#define VSZ 4096   // V
#define NBLK 32    // sinkhorn blocks (32 j-rows each, 512 threads)
#define JPB 32     // j's per sinkhorn block
#define KPAD 1040  // LDS row stride for K (1024 + 16 floats)

// ---------------- softmax(y/2) row-wise, writes u16 fixed-point probs --------
// u16 quantization (x65535) enables v_sad_u16 in cdist: one VALU instr computes
// |a.hi-b.hi|+|a.lo-b.lo|+acc (2 elems + free accumulate) vs 8 instr/8 elems
// for the f16 min+add-tree. Quant error ~1.5e-5/elem, random-walk over V=4096
// -> dW ~ 3e-4 -> final scalar error ~1e-5 after Sinkhorn averaging.
__global__ __launch_bounds__(256) void softmax_kernel(const float* __restrict__ ys,
                                                      const float* __restrict__ yt,
                                                      unsigned short* __restrict__ ps,
                                                      unsigned short* __restrict__ pt) {
    int row = blockIdx.x;
    const float* src;
    unsigned short* dst;
    if (row < BSZ) { src = ys + (size_t)row * VSZ;         dst = ps + (size_t)row * VSZ; }
    else           { src = yt + (size_t)(row - BSZ) * VSZ; dst = pt + (size_t)(row - BSZ) * VSZ; }
    int t = threadIdx.x;
    float4 v[4];
    float m = -1e30f;
#pragma unroll
    for (int k = 0; k < 4; ++k) {
        v[k] = ((const float4*)src)[t + 256 * k];
        m = fmaxf(m, fmaxf(fmaxf(v[k].x, v[k].y), fmaxf(v[k].z, v[k].w)));
    }
#pragma unroll
    for (int d = 32; d >= 1; d >>= 1) m = fmaxf(m, __shfl_down(m, d));
    __shared__ float sred[4];
    __shared__ float sred2[4];
    int lane = t & 63, wid = t >> 6;
    if (lane == 0) sred[wid] = m;
    __syncthreads();
    m = fmaxf(fmaxf(sred[0], sred[1]), fmaxf(sred[2], sred[3]));
    const float C = 0.7213475204444817f;  // 0.5 * log2(e)  (T = 2)
    float s = 0.f;
#pragma unroll
    for (int k = 0; k < 4; ++k) {
        v[k].x = exp2f((v[k].x - m) * C);
        v[k].y = exp2f((v[k].y - m) * C);
        v[k].z = exp2f((v[k].z - m) * C);
        v[k].w = exp2f((v[k].w - m) * C);
        s += (v[k].x + v[k].y) + (v[k].z + v[k].w);
    }
#pragma unroll
    for (int d = 32; d >= 1; d >>= 1) s += __shfl_down(s, d);
    if (lane == 0) sred2[wid] = s;
    __syncthreads();
    s = (sred2[0] + sred2[1]) + (sred2[2] + sred2[3]);
    float inv = 65535.0f / s;  // fold quantization scale into the normalizer
#pragma unroll
    for (int k = 0; k < 4; ++k) {
        union { unsigned short h[4]; uint2 u; } o;
        o.h[0] = (unsigned short)__float2uint_rn(fminf(v[k].x * inv, 65535.0f));
        o.h[1] = (unsigned short)__float2uint_rn(fminf(v[k].y * inv, 65535.0f));
        o.h[2] = (unsigned short)__float2uint_rn(fminf(v[k].z * inv, 65535.0f));
        o.h[3] = (unsigned short)__float2uint_rn(fminf(v[k].w * inv, 65535.0f));
        ((uint2*)dst)[t + 256 * k] = o.u;
    }
}

// ---------------- W-partial: WT[j][i] = sum_v |ps[i,v] - pt[j,v]| ------------
// R16: v_sad_u16 (4 instr / 8 elems, fused abs-diff+reduce+acc) replaces the
// f16 MINACC (8 instr / 8 elems) -> VALU floor 55us -> 27us. LDS now the floor
// (~60us at 69 TB/s). Double-buffered LDS: grid is 1024 blocks = 4 blocks/CU,
// so the old single-buffer-for-8-blocks argument was moot; 36.9KB x 4 = 147KB
// fits 160KB/CU, and we drop one of the two syncthreads per kt.
#define TS 64
#define LSTRH 72  // u16 row stride (144 B): 2-way bank aliasing -> free (m136)

__global__ __launch_bounds__(256) void cdist_kernel(const unsigned short* __restrict__ psh,
                                                    const unsigned short* __restrict__ pth,
                                                    float* __restrict__ spart) {
    // layout: [sP buf0][sP buf1][sQ buf0][sQ buf1], each TS*LSTRH u16
    __shared__ unsigned short lds[4 * TS * LSTRH];   // 36,864 B
    unsigned short* sP0 = lds;
    unsigned short* sQ0 = lds + 2 * TS * LSTRH;
    const int bi = blockIdx.x;
    const int bj = blockIdx.y;
    const int bv = blockIdx.z;
    const int t = threadIdx.x;
    const int cl = t & 15;   // i-lane
    const int rl = t >> 4;   // j-lane
    const unsigned short* psb = psh + ((size_t)bi * TS) * VSZ + bv * 1024;
    const unsigned short* ptb = pth + ((size_t)bj * TS) * VSZ + bv * 1024;
    const int isP = (t < 128);
    const int lt = t & 127;
    const int srow = lt >> 1;            // 0..63
    const int sc0 = (lt & 1) * 32;       // half-offset: 0 or 32
    const unsigned short* gsrc = (isP ? psb : ptb) + (size_t)srow * VSZ + sc0;
    unsigned short* lbase = (isP ? sP0 : sQ0) + srow * LSTRH + sc0;  // buf0 slot

    unsigned a00 = 0u, a01 = 0u, a02 = 0u, a03 = 0u;
    unsigned a10 = 0u, a11 = 0u, a12 = 0u, a13 = 0u;
    unsigned a20 = 0u, a21 = 0u, a22 = 0u, a23 = 0u;
    unsigned a30 = 0u, a31 = 0u, a32 = 0u, a33 = 0u;

    {   // stage tile 0 into buf 0
        uint4 r0 = *(const uint4*)(gsrc + 0);
        uint4 r1 = *(const uint4*)(gsrc + 8);
        uint4 r2 = *(const uint4*)(gsrc + 16);
        uint4 r3 = *(const uint4*)(gsrc + 24);
        *(uint4*)(lbase + 0)  = r0;
        *(uint4*)(lbase + 8)  = r1;
        *(uint4*)(lbase + 16) = r2;
        *(uint4*)(lbase + 24) = r3;
    }
    __syncthreads();

    for (int kt = 0; kt < 16; ++kt) {
        const int cb = kt & 1;
        uint4 rn0, rn1, rn2, rn3;
        if (kt < 15) {  // prefetch next tile into registers (hides HBM latency)
            const unsigned short* g = gsrc + (kt + 1) * 64;
            rn0 = *(const uint4*)(g + 0);
            rn1 = *(const uint4*)(g + 8);
            rn2 = *(const uint4*)(g + 16);
            rn3 = *(const uint4*)(g + 24);
        }
        const unsigned short* pbase = sP0 + cb * (TS * LSTRH) + cl * LSTRH;
        const unsigned short* qbase = sQ0 + cb * (TS * LSTRH) + rl * LSTRH;
#pragma unroll
        for (int vv = 0; vv < 8; ++vv) {
            uint4 p0, p1, p2, p3, q0, q1, q2, q3;
            q0 = *(const uint4*)(qbase + 0 * 16 * LSTRH + vv * 8);
            q1 = *(const uint4*)(qbase + 1 * 16 * LSTRH + vv * 8);
            q2 = *(const uint4*)(qbase + 2 * 16 * LSTRH + vv * 8);
            q3 = *(const uint4*)(qbase + 3 * 16 * LSTRH + vv * 8);
            p0 = *(const uint4*)(pbase + 0 * 16 * LSTRH + vv * 8);
            p1 = *(const uint4*)(pbase + 1 * 16 * LSTRH + vv * 8);
            p2 = *(const uint4*)(pbase + 2 * 16 * LSTRH + vv * 8);
            p3 = *(const uint4*)(pbase + 3 * 16 * LSTRH + vv * 8);
#define SADACC(A, P, Q)                                     \
    A = __builtin_amdgcn_sad_u16(P.x, Q.x, A);              \
    A = __builtin_amdgcn_sad_u16(P.y, Q.y, A);              \
    A = __builtin_amdgcn_sad_u16(P.z, Q.z, A);              \
    A = __builtin_amdgcn_sad_u16(P.w, Q.w, A);
            SADACC(a00, p0, q0) SADACC(a01, p1, q0) SADACC(a02, p2, q0) SADACC(a03, p3, q0)
            SADACC(a10, p0, q1) SADACC(a11, p1, q1) SADACC(a12, p2, q1) SADACC(a13, p3, q1)
            SADACC(a20, p0, q2) SADACC(a21, p1, q2) SADACC(a22, p2, q2) SADACC(a23, p3, q2)
            SADACC(a30, p0, q3) SADACC(a31, p1, q3) SADACC(a32, p2, q3) SADACC(a33, p3, q3)
#undef SADACC
        }
        if (kt < 15) {
            // write NEXT tile into the other buffer; current readers untouched.
            unsigned short* lw = lbase + (cb ^ 1) * (TS * LSTRH);
            *(uint4*)(lw + 0)  = rn0;
            *(uint4*)(lw + 8)  = rn1;
            *(uint4*)(lw + 16) = rn2;
            *(uint4*)(lw + 24) = rn3;
            __syncthreads();  // one sync per kt: writes visible + reads of cb done
        }
    }

    float* outp = spart + (size_t)bv * (BSZ * BSZ);
    const float SCL = 1.0f / 65535.0f;
    unsigned accs[4][4] = {{a00, a01, a02, a03},
                           {a10, a11, a12, a13},
                           {a20, a21, a22, a23},
                           {a30, a31, a32, a33}};
#pragma unroll
    for (int w = 0; w < 4; ++w) {
        int jr = bj * TS + rl + 16 * w;
#pragma unroll
        for (int u = 0; u < 4; ++u) {
            int ic = bi * TS + cl + 16 * u;
            outp[(size_t)jr * BSZ + ic] = (float)accs[w][u] * SCL;
        }
    }
}

// ------- combine v-partials: W = sum parts (direct L1), K = exp(-W/eps) ------
__global__ __launch_bounds__(256) void combine_kernel(const float* __restrict__ spart,
                                                      float* __restrict__ wt,
                                                      float* __restrict__ kt,
                                                      unsigned* __restrict__ flags) {
    if (blockIdx.x == 0 && threadIdx.x < NBLK) flags[threadIdx.x * 32] = 0u;
    int idx = blockIdx.x * 256 + threadIdx.x;  // over B*B/4 float4s
    const float4* p0 = (const float4*)spart;
    const int Q = (BSZ * BSZ) / 4;
    float4 a = p0[idx], b = p0[idx + Q], c = p0[idx + 2 * Q], d = p0[idx + 3 * Q];
    float4 w;
    w.x = (a.x + b.x) + (c.x + d.x);
    w.y = (a.y + b.y) + (c.y + d.y);
    w.z = (a.z + b.z) + (c.z + d.z);
    w.w = (a.w + b.w) + (c.w + d.w);
    ((float4*)wt)[idx] = w;
    const float CE = -14.426950408889634f;  // -log2(e)/eps, eps=0.1
    float4 k;
    k.x = exp2f(w.x * CE);
    k.y = exp2f(w.y * CE);
    k.z = exp2f(w.z * CE);
    k.w = exp2f(w.w * CE);
    ((float4*)kt)[idx] = k;
}

// ------- grid barrier v4: all-to-all (no master/go relay hop) -----------------
__device__ inline void grid_barrier(unsigned* flags, unsigned gen) {
    __syncthreads();
    const int t = threadIdx.x;
    if (t == 0)  // RELEASE: flush this block's cpart/outpart stores
        __hip_atomic_store(&flags[blockIdx.x * 32], gen, __ATOMIC_RELEASE, __HIP_MEMORY_SCOPE_AGENT);
    if (t < NBLK) {
        while (__hip_atomic_load(&flags[t * 32], __ATOMIC_RELAXED, __HIP_MEMORY_SCOPE_AGENT) < gen)
            __builtin_amdgcn_s_sleep(1);
    }
    __syncthreads();
    if (t == 0)  // single ACQUIRE: one L1/L2 inv for the whole block
        (void)__hip_atomic_load(&flags[0], __ATOMIC_ACQUIRE, __HIP_MEMORY_SCOPE_AGENT);
    __syncthreads();
}

// ---------------- Sinkhorn: a = 1/(K b); b = 1/(K^T a), 20 iters + final sum --
__global__ __launch_bounds__(512) void sinkhorn_kernel(const float* __restrict__ KT,
                                                       const float* __restrict__ WT,
                                                       float* __restrict__ cpart,
                                                       float* __restrict__ outpart,
                                                       float* __restrict__ out,
                                                       unsigned* __restrict__ flags) {
    __shared__ __align__(16) float k_lds[JPB * KPAD];   // 133,120 B
    __shared__ __align__(16) float a_sh[BSZ];
    __shared__ float b_sh[JPB];
    __shared__ float red[JPB];
    const int z = blockIdx.x;
    const int t = threadIdx.x;
    const int j0 = z * JPB;
#pragma unroll
    for (int m = 0; m < 16; ++m) {
        int idx = t + 512 * m;
        int row = idx >> 8;
        int col = (idx & 255) * 4;
        float4 v = *(const float4*)(KT + (size_t)(j0 + row) * BSZ + col);
        *(float4*)(&k_lds[row * KPAD + col]) = v;
    }
    if (t < JPB) b_sh[t] = 1.0f;
    __syncthreads();
    const int jj = t >> 4;   // 0..31
    const int il = t & 15;
    unsigned gen = 1u;
    for (int it = 0; it < 20; ++it) {
        float* cur = cpart + (size_t)(it & 1) * (NBLK * BSZ) + (size_t)z * BSZ;
        float2 s = {0.f, 0.f};
#pragma unroll
        for (int q = 0; q < JPB; ++q) {
            float2 kv = *(const float2*)(&k_lds[q * KPAD + 2 * t]);
            float bb = b_sh[q];
            s.x += kv.x * bb; s.y += kv.y * bb;
        }
        ((float2*)cur)[t] = s;
        grid_barrier(flags, gen++);
        const float* curAll = cpart + (size_t)(it & 1) * (NBLK * BSZ);
        float2 c = {0.f, 0.f};
#pragma unroll 8
        for (int zz = 0; zz < NBLK; ++zz) {
            float2 v = ((const float2*)curAll)[zz * 512 + t];
            c.x += v.x; c.y += v.y;
        }
        float2 ar;
        ar.x = 1.0f / c.x; ar.y = 1.0f / c.y;
        ((float2*)a_sh)[t] = ar;
        __syncthreads();
        float sb = 0.f;
#pragma unroll
        for (int m2 = 0; m2 < 16; ++m2) {
            float4 kv = *(const float4*)(&k_lds[jj * KPAD + (il + 16 * m2) * 4]);
            float4 av = ((const float4*)a_sh)[il + 16 * m2];
            sb += (kv.x * av.x + kv.y * av.y) + (kv.z * av.z + kv.w * av.w);
        }
#pragma unroll
        for (int d = 8; d >= 1; d >>= 1) sb += __shfl_down(sb, d, 16);
        if (il == 0) b_sh[jj] = 1.0f / sb;
        __syncthreads();
    }
    {
        const float4* wrow = (const float4*)(WT + (size_t)(j0 + jj) * BSZ);
        float sb = 0.f;
#pragma unroll 4
        for (int m2 = 0; m2 < 16; ++m2) {
            float4 kv = *(const float4*)(&k_lds[jj * KPAD + (il + 16 * m2) * 4]);
            float4 wv = wrow[il + 16 * m2];
            float4 av = ((const float4*)a_sh)[il + 16 * m2];
            sb += (av.x * kv.x * wv.x + av.y * kv.y * wv.y) +
                  (av.z * kv.z * wv.z + av.w * kv.w * wv.w);
        }
#pragma unroll
        for (int d = 8; d >= 1; d >>= 1) sb += __shfl_down(sb, d, 16);
        if (il == 0) red[jj] = sb * b_sh[jj];
        __syncthreads();
        if (t == 0) {
            float ss = 0.f;
#pragma unroll
            for (int q = 0; q < JPB; ++q) ss += red[q];
            outpart[z] = ss;
        }
    }
    grid_barrier(flags, gen++);
    if (z == 0 && t == 0) {
        float ss = 0.f;
        for (int q = 0; q < NBLK; ++q) ss += outpart[q];
        out[0] = 0.001f * ss;
    }
}

extern "C" void kernel_launch(void* const* d_in, const int* in_sizes, int n_in,
                              void* d_out, int out_size, void* d_ws, size_t ws_size,
                              hipStream_t stream) {
    const float* ys = (const float*)d_in[0];
    const float* yt = (const float*)d_in[1];
    float* ws = (float*)d_ws;
    unsigned short* psh = (unsigned short*)ws;                        // 2M u16 in 1M floats... (same bytes as before)
    unsigned short* pth = (unsigned short*)(ws + 2ull * 1024 * 1024); // offset in floats, matches old layout
    float* spart   = ws + 4ull * 1024 * 1024;              // 4 x 1M
    float* wt      = spart + 4ull * BSZ * BSZ;             // 1M
    float* kt      = wt + (size_t)BSZ * BSZ;               // 1M
    float* cpart   = kt + (size_t)BSZ * BSZ;               // 2*32*1024
    float* outpart = cpart + 2ull * NBLK * BSZ;            // 32 (+pad)
    unsigned* flags = (unsigned*)(outpart + 128);          // NBLK x 32 uints
    float* outp    = (float*)d_out;

    softmax_kernel<<<dim3(2 * BSZ), dim3(256), 0, stream>>>(ys, yt, psh, pth);
    cdist_kernel<<<dim3(16, 16, 4), dim3(256), 0, stream>>>(psh, pth, spart);
    combine_kernel<<<dim3((BSZ * BSZ / 4) / 256), dim3(256), 0, stream>>>(spart, wt, kt, flags);

    void* args[] = {(void*)&kt, (void*)&wt, (void*)&cpart, (void*)&outpart, (void*)&outp,
                    (void*)&flags};
    (void)hipLaunchCooperativeKernel((void*)sinkhorn_kernel, dim3(NBLK), dim3(512), args, 0, stream);
}